// Round 1
// baseline (487.691 us; speedup 1.0000x reference)
//
#include <hip/hip_runtime.h>

typedef unsigned short ushort_t;
typedef unsigned char uchar_t;
typedef __bf16 bf16x8 __attribute__((ext_vector_type(8)));
typedef float f32x4 __attribute__((ext_vector_type(4)));

__device__ __forceinline__ ushort_t f2bf(float f) {
  unsigned u = __float_as_uint(f);
  u += 0x7fff + ((u >> 16) & 1);
  return (ushort_t)(u >> 16);
}

__device__ __forceinline__ void gload16(const void* g, void* l) {
  __builtin_amdgcn_global_load_lds(
      (const __attribute__((address_space(1))) unsigned int*)g,
      (__attribute__((address_space(3))) unsigned int*)l, 16, 0, 0);
}

// ---------------- weight fp32 -> bf16, pack qk bias, zero stats2 ----------------
__global__ __launch_bounds__(256) void cvt_weights(
    const float* __restrict__ wq, const float* __restrict__ wk,
    const float* __restrict__ wv, const float* __restrict__ wo,
    const float* __restrict__ bq, const float* __restrict__ bk,
    ushort_t* __restrict__ dst, float* __restrict__ qkbias,
    float* __restrict__ stats2) {
  int b = blockIdx.x, t = threadIdx.x;
  if (b < 1024) {
    int i = b * 256 + t;
    dst[i]          = f2bf(wq[i]);
    dst[262144 + i] = f2bf(wk[i]);
    dst[524288 + i] = f2bf(wv[i]);
    dst[786432 + i] = f2bf(wo[i]);
  } else if (b < 1028) {
    int j = (b - 1024) * 256 + t;  // 0..1023
    qkbias[j] = (j < 512) ? bq[j] : bk[j - 512];
  } else {
    if (t < 128) stats2[t] = 0.f;
  }
}

// ---------------- zero the rowsum accumulator ----------------
__global__ __launch_bounds__(256) void zero_f32(float* __restrict__ p) {
  p[blockIdx.x * 256 + threadIdx.x] = 0.f;
}

// ---------------- group norm partial stats: 4 blocks per (b,g) ----------------
__global__ __launch_bounds__(256) void gn_stats_partial(const float* __restrict__ x,
                                                        float* __restrict__ stats2) {
  int bg = blockIdx.x >> 2, q = blockIdx.x & 3;
  const float4* p = (const float4*)(x + (size_t)bg * 65536 + q * 16384);
  float s = 0.f, ss = 0.f;
  for (int i = threadIdx.x; i < 4096; i += 256) {
    float4 v = p[i];
    s += v.x + v.y + v.z + v.w;
    ss += v.x * v.x + v.y * v.y + v.z * v.z + v.w * v.w;
  }
  for (int off = 32; off; off >>= 1) {
    s += __shfl_xor(s, off, 64);
    ss += __shfl_xor(ss, off, 64);
  }
  __shared__ float sh[8];
  int wave = threadIdx.x >> 6, lane = threadIdx.x & 63;
  if (lane == 0) { sh[wave] = s; sh[4 + wave] = ss; }
  __syncthreads();
  if (threadIdx.x == 0) {
    atomicAdd(&stats2[bg * 2], sh[0] + sh[1] + sh[2] + sh[3]);
    atomicAdd(&stats2[bg * 2 + 1], sh[4] + sh[5] + sh[6] + sh[7]);
  }
}

__global__ __launch_bounds__(64) void gn_finalize(const float* __restrict__ stats2,
                                                  float* __restrict__ stats) {
  int t = threadIdx.x;  // 64 groups total (2 batches x 32)
  float s = stats2[t * 2], ss = stats2[t * 2 + 1];
  float mean = s * (1.f / 65536.f);
  float var = ss * (1.f / 65536.f) - mean * mean;
  stats[t * 2] = mean;
  stats[t * 2 + 1] = rsqrtf(var + 1e-6f);
}

// ---------------- GN apply + transpose: x (b,c,n) -> hnT (b,n,c) bf16 ----------------
__global__ __launch_bounds__(256) void gn_apply(
    const float* __restrict__ x, const float* __restrict__ gamma,
    const float* __restrict__ beta, const float* __restrict__ stats,
    ushort_t* __restrict__ hnT) {
  __shared__ float T[32][33];
  int i0 = blockIdx.x * 32, c0 = blockIdx.y * 32, b = blockIdx.z;
  int tx = threadIdx.x, ty = threadIdx.y;  // (32,8)
#pragma unroll
  for (int k = 0; k < 4; k++) {
    int cl = ty + k * 8;
    int c = c0 + cl;
    int bg = (b * 32 + (c >> 4)) * 2;
    float mean = stats[bg], rstd = stats[bg + 1];
    float v = x[((size_t)(b * 512 + c)) * 4096 + i0 + tx];
    T[cl][tx] = (v - mean) * rstd * gamma[c] + beta[c];
  }
  __syncthreads();
#pragma unroll
  for (int k = 0; k < 4; k++) {
    int il = ty + k * 8;
    hnT[((size_t)b * 4096 + i0 + il) * 512 + c0 + tx] = f2bf(T[tx][il]);
  }
}

// ---------------- bf16 C = A * B^T GEMM, 128 x BN tile (round-5 engine) -------
// omode: 0 = bf16 out, 1 = fp32 + residual, 2 = fp8 e4m3 out.
template <int BN>
__global__ __launch_bounds__(256) void gemm_abt(
    const ushort_t* __restrict__ A, long long sA, int lda,
    const ushort_t* __restrict__ B, long long sB, int ldb,
    int K, int N, int ldc,
    ushort_t* __restrict__ outB, long long sC,
    const float* __restrict__ bias, int bias_mode, float scale,
    float* __restrict__ outF, const float* __restrict__ resid,
    float* __restrict__ rowsum, const float* __restrict__ colscale,
    int swiz, int omode) {
  constexpr int CPW = (8 + BN / 16) / 4;
  constexpr int SB = (128 + BN) * 32;      // halfwords per LDS buffer
  constexpr int MI = (BN == 128) ? 4 : 2;
  constexpr int NI = 4;
  __shared__ __align__(16) ushort_t Ls[2][SB];

  int bx = blockIdx.x, by = blockIdx.y, bz = blockIdx.z;
  if (swiz) {
    unsigned nx = gridDim.x, ny = gridDim.y;
    unsigned id = (blockIdx.z * ny + blockIdx.y) * nx + blockIdx.x;
    unsigned pb8 = (nx * ny) >> 3;
    unsigned c = id & 7, j = id >> 3;
    bz = j / pb8;
    unsigned jb = j - bz * pb8;
    unsigned jy = jb / nx;
    by = c * (ny >> 3) + jy;
    bx = jb - jy * nx;
  }

  int m0 = by * 128, n0 = bx * BN;
  int t = threadIdx.x;
  int lane = t & 63;
  int quad = lane >> 4, l16 = lane & 15;
  int wave = t >> 6;
  int wm = (BN == 128) ? (wave >> 1) * 64 : wave * 32;
  int wn = (BN == 128) ? (wave & 1) * 64 : 0;

  f32x4 acc[MI][NI];
#pragma unroll
  for (int i = 0; i < MI; i++)
#pragma unroll
    for (int j = 0; j < NI; j++)
#pragma unroll
      for (int r = 0; r < 4; r++) acc[i][j][r] = 0.f;

  const ushort_t* gp[CPW];
  int lofs[CPW];
  int crow = lane >> 2, skoff = (lane & 3) * 8;
#pragma unroll
  for (int i = 0; i < CPW; i++) {
    int c = wave * CPW + i;
    if (c < 8) {
      gp[i] = A + (size_t)bz * sA + (size_t)(m0 + c * 16 + crow) * lda + skoff;
      lofs[i] = c * 1024 + lane * 16;
    } else {
      int slot = (c - 8) * 16 + crow;
      int arow = (slot & ~63) + ((slot & 15) * 4) + ((slot & 63) >> 4);
      gp[i] = B + (size_t)bz * sB + (size_t)(n0 + arow) * ldb + skoff;
      lofs[i] = 8192 + (c - 8) * 1024 + lane * 16;
    }
  }
  char* lbase = (char*)&Ls[0][0];

#pragma unroll
  for (int i = 0; i < CPW; i++) gload16(gp[i], lbase + lofs[i]);

  for (int k0 = 0; k0 < K; k0 += 32) {
    int p = (k0 >> 5) & 1;
    __syncthreads();
    if (k0 + 32 < K) {
      int pofs = (p ^ 1) * (SB * 2);
#pragma unroll
      for (int i = 0; i < CPW; i++) gload16(gp[i] + k0 + 32, lbase + pofs + lofs[i]);
    }
    bf16x8 af[MI], bfr[NI];
#pragma unroll
    for (int i = 0; i < MI; i++)
      af[i] = *(const bf16x8*)&Ls[p][(wm + i * 16 + l16) * 32 + quad * 8];
#pragma unroll
    for (int j = 0; j < NI; j++)
      bfr[j] = *(const bf16x8*)&Ls[p][4096 + (wn + j * 16 + l16) * 32 + quad * 8];
#pragma unroll
    for (int mi = 0; mi < MI; mi++)
#pragma unroll
      for (int ni = 0; ni < NI; ni++)
        acc[mi][ni] = __builtin_amdgcn_mfma_f32_16x16x32_bf16(af[mi], bfr[ni], acc[mi][ni], 0, 0, 0);
  }

  size_t cbase = (size_t)bz * sC;
  int gnb = n0 + wn + l16 * 4;
  float cs4[4] = {1.f, 1.f, 1.f, 1.f};
  if (colscale) {
    float4 c4 = *(const float4*)&colscale[(size_t)bz * N + gnb];
    cs4[0] = 1.f / c4.x; cs4[1] = 1.f / c4.y; cs4[2] = 1.f / c4.z; cs4[3] = 1.f / c4.w;
  }
  float b4[4] = {0.f, 0.f, 0.f, 0.f};
  if (bias_mode == 2) {
    float4 t4 = *(const float4*)&bias[gnb];
    b4[0] = t4.x; b4[1] = t4.y; b4[2] = t4.z; b4[3] = t4.w;
  }
#pragma unroll
  for (int mi = 0; mi < MI; mi++) {
#pragma unroll
    for (int r = 0; r < 4; r++) {
      int m = m0 + wm + mi * 16 + quad * 4 + r;
      float rbias = (bias_mode == 1) ? bias[m] : 0.f;
      float v4[4];
      float rs = 0.f;
#pragma unroll
      for (int ni = 0; ni < NI; ni++) {
        float val = acc[mi][ni][r];
        if (colscale) val *= cs4[ni];
        val += (bias_mode == 2) ? b4[ni] : rbias;
        val *= scale;
        if (rowsum) { val = __expf(val) * 0.0625f; rs += val; }
        v4[ni] = val;
      }
      size_t idx = cbase + (size_t)m * ldc + gnb;
      if (omode == 1) {
        float4 rv = *(const float4*)&resid[idx];
        float4 ov = make_float4(v4[0] + rv.x, v4[1] + rv.y, v4[2] + rv.z, v4[3] + rv.w);
        *(float4*)&outF[idx] = ov;
      } else if (omode == 2) {
        unsigned w = __builtin_amdgcn_cvt_pk_fp8_f32(v4[0], v4[1], 0u, false);
        w = __builtin_amdgcn_cvt_pk_fp8_f32(v4[2], v4[3], w, true);
        *(unsigned*)&((uchar_t*)outB)[idx] = w;
      } else {
        unsigned lo = (unsigned)f2bf(v4[0]) | ((unsigned)f2bf(v4[1]) << 16);
        unsigned hi = (unsigned)f2bf(v4[2]) | ((unsigned)f2bf(v4[3]) << 16);
        *(uint2*)&outB[idx] = make_uint2(lo, hi);
      }
      if (rowsum) {
        rs += __shfl_xor(rs, 1, 64);
        rs += __shfl_xor(rs, 2, 64);
        rs += __shfl_xor(rs, 4, 64);
        rs += __shfl_xor(rs, 8, 64);
        if (l16 == 0) atomicAdd(&rowsum[(size_t)bz * 4096 + m], rs);
      }
    }
  }
}

// ---------------- fp8 C = A * B^T GEMM, 128 x BN tile, BK=32 ------------------
// BK=32 row-major chunk staging: LDS byte o holds (row = o>>5, kbyte = o&31);
// rows 0..127 = A tile, rows 128.. = B tile (column-permuted per 64-row group
// so the epilogue can write 4 consecutive fp8/bf16 columns per lane).
// b64 fragment read banks: 8*(l16&3)+2*quad -> all 32 banks x 4 dwords = the
// wave64-b64 minimum (conflict-free in the m136 sense).
// LDS halves vs BK=64 (16KB / 12KB per wg) -> 8 wg/CU co-resident (TLP to hide
// the vmcnt-drain at each barrier; pinned by __launch_bounds__(256,8)).
// omode 0: bf16 out. omode 2: exp(scale*acc)/16 -> fp8 out + rowsum.
template <int BN>
__global__ __launch_bounds__(256, 8) void gemm_fp8(
    const uchar_t* __restrict__ A, long long sA, int lda,
    const uchar_t* __restrict__ B, long long sB, int ldb,
    int K, int ldc,
    void* __restrict__ outp, long long sC,
    float scale, float* __restrict__ rowsum, int swiz, int omode) {
  constexpr int ROWS = 128 + BN;
  constexpr int SBB = ROWS * 32;           // bytes per buffer
  constexpr int NP = (SBB + 4095) / 4096;  // staging passes (256 thr x 16B)
  constexpr bool EXACT = (SBB % 4096) == 0;
  constexpr int MI = (BN == 128) ? 4 : 2;
  constexpr int NI = 4;
  __shared__ __align__(16) uchar_t Ls[2][SBB];

  int bx = blockIdx.x, by = blockIdx.y, bz = blockIdx.z;
  if (swiz) {
    unsigned nx = gridDim.x, ny = gridDim.y;
    unsigned id = (blockIdx.z * ny + blockIdx.y) * nx + blockIdx.x;
    unsigned pb8 = (nx * ny) >> 3;
    unsigned c = id & 7, j = id >> 3;
    bz = j / pb8;
    unsigned jb = j - bz * pb8;
    unsigned jy = jb / nx;
    by = c * (ny >> 3) + jy;
    bx = jb - jy * nx;
  }

  int m0 = by * 128, n0 = bx * BN;
  int t = threadIdx.x;
  int lane = t & 63;
  int quad = lane >> 4, l16 = lane & 15;
  int wave = t >> 6;
  int wm = (BN == 128) ? (wave >> 1) * 64 : wave * 32;
  int wn = (BN == 128) ? (wave & 1) * 64 : 0;

  f32x4 acc[MI][NI];
#pragma unroll
  for (int i = 0; i < MI; i++)
#pragma unroll
    for (int j = 0; j < NI; j++)
#pragma unroll
      for (int r = 0; r < 4; r++) acc[i][j][r] = 0.f;

  // row-major BK=32 staging map: LDS offset o <-> (row o>>5, seg o&16)
  const uchar_t* gp[NP];
  int lofs[NP];
  bool act[NP];
#pragma unroll
  for (int i = 0; i < NP; i++) {
    int o = i * 4096 + t * 16;
    act[i] = EXACT || (o < SBB);
    int oo = act[i] ? o : 0;
    int row = oo >> 5, seg = oo & 16;
    if (row < 128) {
      gp[i] = A + (size_t)bz * sA + (size_t)(m0 + row) * lda + seg;
    } else {
      int br = row - 128;
      int g = br & ~63, loc = br & 63;
      int ar = g + (loc & 15) * 4 + (loc >> 4);
      gp[i] = B + (size_t)bz * sB + (size_t)(n0 + ar) * ldb + seg;
    }
    lofs[i] = oo;
  }
  char* lbase = (char*)&Ls[0][0];

#pragma unroll
  for (int i = 0; i < NP; i++)
    if (act[i]) gload16(gp[i], lbase + lofs[i]);

  int vb = l16 * 32 + quad * 8;
  for (int k0 = 0; k0 < K; k0 += 32) {
    int p = (k0 >> 5) & 1;
    __syncthreads();
    if (k0 + 32 < K) {
      int pofs = (p ^ 1) * SBB;
#pragma unroll
      for (int i = 0; i < NP; i++)
        if (act[i]) gload16(gp[i] + k0 + 32, lbase + pofs + lofs[i]);
    }
    const uchar_t* Lp = &Ls[p][0];
    long long af[MI], bfv[NI];
#pragma unroll
    for (int i = 0; i < MI; i++)
      af[i] = *(const long long*)&Lp[wm * 32 + i * 512 + vb];
#pragma unroll
    for (int j = 0; j < NI; j++)
      bfv[j] = *(const long long*)&Lp[4096 + wn * 32 + j * 512 + vb];
#pragma unroll
    for (int mi = 0; mi < MI; mi++)
#pragma unroll
      for (int ni = 0; ni < NI; ni++)
        acc[mi][ni] = __builtin_amdgcn_mfma_f32_16x16x32_fp8_fp8(af[mi], bfv[ni], acc[mi][ni], 0, 0, 0);
  }

  size_t cbase = (size_t)bz * sC;
  int gnb = n0 + wn + l16 * 4;
#pragma unroll
  for (int mi = 0; mi < MI; mi++) {
#pragma unroll
    for (int r = 0; r < 4; r++) {
      int m = m0 + wm + mi * 16 + quad * 4 + r;
      if (omode == 2) {
        float v4[4];
        float rs = 0.f;
#pragma unroll
        for (int ni = 0; ni < NI; ni++) {
          v4[ni] = __expf(acc[mi][ni][r] * scale) * 0.0625f;
          rs += v4[ni];
        }
        unsigned w = __builtin_amdgcn_cvt_pk_fp8_f32(v4[0], v4[1], 0u, false);
        w = __builtin_amdgcn_cvt_pk_fp8_f32(v4[2], v4[3], w, true);
        *(unsigned*)&((uchar_t*)outp)[cbase + (size_t)m * ldc + gnb] = w;
        rs += __shfl_xor(rs, 1, 64);
        rs += __shfl_xor(rs, 2, 64);
        rs += __shfl_xor(rs, 4, 64);
        rs += __shfl_xor(rs, 8, 64);
        if (l16 == 0) atomicAdd(&rowsum[(size_t)bz * 4096 + m], rs);
      } else {
        unsigned lo = (unsigned)f2bf(acc[mi][0][r]) | ((unsigned)f2bf(acc[mi][1][r]) << 16);
        unsigned hi = (unsigned)f2bf(acc[mi][2][r]) | ((unsigned)f2bf(acc[mi][3][r]) << 16);
        *(uint2*)&((ushort_t*)outp)[cbase + (size_t)m * ldc + gnb] = make_uint2(lo, hi);
      }
    }
  }
}

extern "C" void kernel_launch(void* const* d_in, const int* in_sizes, int n_in,
                              void* d_out, int out_size, void* d_ws, size_t ws_size,
                              hipStream_t stream) {
  const float* x     = (const float*)d_in[0];
  const float* gamma = (const float*)d_in[1];
  const float* beta  = (const float*)d_in[2];
  const float* wq    = (const float*)d_in[3];
  const float* bq    = (const float*)d_in[4];
  const float* wk    = (const float*)d_in[5];
  const float* bk    = (const float*)d_in[6];
  const float* wv    = (const float*)d_in[7];
  const float* bv    = (const float*)d_in[8];
  const float* wo    = (const float*)d_in[9];
  const float* bo    = (const float*)d_in[10];
  float* out = (float*)d_out;

  // workspace layout
  ushort_t* wb  = (ushort_t*)d_ws;     // [wq;wk] 1024x512, wv, wo (bf16)
  ushort_t* wvb = wb + 524288;
  ushort_t* wob = wb + 786432;
  ushort_t* hnT = wb + 1048576;        // 2 x 4096 x 512 bf16
  uchar_t*  qk8 = (uchar_t*)(hnT + 4194304);  // 2 x 4096 x 1024 fp8 (q | k)
  uchar_t*  vC8 = qk8 + 8388608;       // 2 x 512 x 4096 fp8
  ushort_t* OT  = (ushort_t*)(vC8 + 4194304); // 2 x 4096 x 512 bf16
  uchar_t*  S8  = (uchar_t*)(OT + 4194304);   // 2 x 4096 x 4096 fp8 (P' = exp/16)
  float* fbuf   = (float*)(S8 + 33554432);
  float* stats  = fbuf;                // 128
  float* stats2 = fbuf + 128;          // 128
  float* qkbias = fbuf + 256;          // 1024
  float* l      = (float*)hnT;         // 2 x 4096 row sums (hnT dead after v-GEMM)

  const long long HS = 2097152;   // 4096*512 per batch
  const long long QS = 4194304;   // 4096*1024 per batch (bytes, fp8)
  const long long SS = 16777216;  // 4096*4096 per batch (bytes, fp8)
  const float scale = 0.044194173824159216f;  // 512^-0.5

  cvt_weights<<<dim3(1029), dim3(256), 0, stream>>>(wq, wk, wv, wo, bq, bk, wb, qkbias, stats2);
  gn_stats_partial<<<dim3(256), dim3(256), 0, stream>>>(x, stats2);
  gn_finalize<<<dim3(1), dim3(64), 0, stream>>>(stats2, stats);
  gn_apply<<<dim3(128, 16, 2), dim3(32, 8), 0, stream>>>(x, gamma, beta, stats, hnT);
  // qk8 = hnT * [wq;wk]^T (M=4096, N=1024, K=512), packed col bias, fp8 out, unscaled
  gemm_abt<128><<<dim3(8, 32, 2), dim3(256), 0, stream>>>(
      hnT, HS, 512, wb, 0, 512, 512, 1024, 1024, (ushort_t*)qk8, QS, qkbias, 2, 1.f,
      nullptr, nullptr, nullptr, nullptr, 1, 2);
  // vC8 = wv * hnT^T (M=512, N=4096, K=512), row bias, fp8 out
  gemm_abt<64><<<dim3(64, 4, 2), dim3(256), 0, stream>>>(
      wvb, 0, 512, hnT, HS, 512, 512, 4096, 4096, (ushort_t*)vC8, HS, bv, 1, 1.f,
      nullptr, nullptr, nullptr, nullptr, 0, 2);
  // hnT dead; reuse as rowsum l
  zero_f32<<<dim3(32), dim3(256), 0, stream>>>(l);
  // P' = exp(scale * q*k^T)/16 fp8 + fused row sums (fp8 MFMA, M=N=4096, K=512)
  gemm_fp8<128><<<dim3(32, 32, 2), dim3(256), 0, stream>>>(
      qk8, QS, 1024, qk8 + 512, QS, 1024, 512, 4096, S8, SS, scale, l, 1, 2);
  // OT = P' * vC8^T (fp8 MFMA, M=4096, N=512, K=4096), bf16 out, swizzled
  gemm_fp8<64><<<dim3(8, 32, 2), dim3(256), 0, stream>>>(
      S8, SS, 4096, vC8, HS, 4096, 4096, 512, OT, HS, 1.f, nullptr, 1, 0);
  // y = wo * (OT/l')^T + bo + x (M=512, N=4096, K=512), fp32 + residual
  gemm_abt<64><<<dim3(64, 4, 2), dim3(256), 0, stream>>>(
      wob, 0, 512, OT, HS, 512, 512, 4096, 4096, nullptr, HS, bo, 1, 1.f,
      out, x, nullptr, l, 0, 1);
}

// Round 2
// 249.858 us; speedup vs baseline: 1.9519x; 1.9519x over previous
//
#include <hip/hip_runtime.h>

typedef unsigned short ushort_t;
typedef unsigned char uchar_t;
typedef __bf16 bf16x8 __attribute__((ext_vector_type(8)));
typedef float f32x4 __attribute__((ext_vector_type(4)));

__device__ __forceinline__ ushort_t f2bf(float f) {
  unsigned u = __float_as_uint(f);
  u += 0x7fff + ((u >> 16) & 1);
  return (ushort_t)(u >> 16);
}

__device__ __forceinline__ void gload16(const void* g, void* l) {
  __builtin_amdgcn_global_load_lds(
      (const __attribute__((address_space(1))) unsigned int*)g,
      (__attribute__((address_space(3))) unsigned int*)l, 16, 0, 0);
}

// ---------------- weight fp32 -> bf16, pack qk bias, zero stats2 ----------------
__global__ __launch_bounds__(256) void cvt_weights(
    const float* __restrict__ wq, const float* __restrict__ wk,
    const float* __restrict__ wv, const float* __restrict__ wo,
    const float* __restrict__ bq, const float* __restrict__ bk,
    ushort_t* __restrict__ dst, float* __restrict__ qkbias,
    float* __restrict__ stats2) {
  int b = blockIdx.x, t = threadIdx.x;
  if (b < 1024) {
    int i = b * 256 + t;
    dst[i]          = f2bf(wq[i]);
    dst[262144 + i] = f2bf(wk[i]);
    dst[524288 + i] = f2bf(wv[i]);
    dst[786432 + i] = f2bf(wo[i]);
  } else if (b < 1028) {
    int j = (b - 1024) * 256 + t;  // 0..1023
    qkbias[j] = (j < 512) ? bq[j] : bk[j - 512];
  } else {
    if (t < 128) stats2[t] = 0.f;
  }
}

// ---------------- zero the rowsum accumulator ----------------
__global__ __launch_bounds__(256) void zero_f32(float* __restrict__ p) {
  p[blockIdx.x * 256 + threadIdx.x] = 0.f;
}

// ---------------- group norm partial stats: 4 blocks per (b,g) ----------------
__global__ __launch_bounds__(256) void gn_stats_partial(const float* __restrict__ x,
                                                        float* __restrict__ stats2) {
  int bg = blockIdx.x >> 2, q = blockIdx.x & 3;
  const float4* p = (const float4*)(x + (size_t)bg * 65536 + q * 16384);
  float s = 0.f, ss = 0.f;
  for (int i = threadIdx.x; i < 4096; i += 256) {
    float4 v = p[i];
    s += v.x + v.y + v.z + v.w;
    ss += v.x * v.x + v.y * v.y + v.z * v.z + v.w * v.w;
  }
  for (int off = 32; off; off >>= 1) {
    s += __shfl_xor(s, off, 64);
    ss += __shfl_xor(ss, off, 64);
  }
  __shared__ float sh[8];
  int wave = threadIdx.x >> 6, lane = threadIdx.x & 63;
  if (lane == 0) { sh[wave] = s; sh[4 + wave] = ss; }
  __syncthreads();
  if (threadIdx.x == 0) {
    atomicAdd(&stats2[bg * 2], sh[0] + sh[1] + sh[2] + sh[3]);
    atomicAdd(&stats2[bg * 2 + 1], sh[4] + sh[5] + sh[6] + sh[7]);
  }
}

__global__ __launch_bounds__(64) void gn_finalize(const float* __restrict__ stats2,
                                                  float* __restrict__ stats) {
  int t = threadIdx.x;  // 64 groups total (2 batches x 32)
  float s = stats2[t * 2], ss = stats2[t * 2 + 1];
  float mean = s * (1.f / 65536.f);
  float var = ss * (1.f / 65536.f) - mean * mean;
  stats[t * 2] = mean;
  stats[t * 2 + 1] = rsqrtf(var + 1e-6f);
}

// ---------------- GN apply + transpose: x (b,c,n) -> hnT (b,n,c) bf16 ----------------
__global__ __launch_bounds__(256) void gn_apply(
    const float* __restrict__ x, const float* __restrict__ gamma,
    const float* __restrict__ beta, const float* __restrict__ stats,
    ushort_t* __restrict__ hnT) {
  __shared__ float T[32][33];
  int i0 = blockIdx.x * 32, c0 = blockIdx.y * 32, b = blockIdx.z;
  int tx = threadIdx.x, ty = threadIdx.y;  // (32,8)
#pragma unroll
  for (int k = 0; k < 4; k++) {
    int cl = ty + k * 8;
    int c = c0 + cl;
    int bg = (b * 32 + (c >> 4)) * 2;
    float mean = stats[bg], rstd = stats[bg + 1];
    float v = x[((size_t)(b * 512 + c)) * 4096 + i0 + tx];
    T[cl][tx] = (v - mean) * rstd * gamma[c] + beta[c];
  }
  __syncthreads();
#pragma unroll
  for (int k = 0; k < 4; k++) {
    int il = ty + k * 8;
    hnT[((size_t)b * 4096 + i0 + il) * 512 + c0 + tx] = f2bf(T[tx][il]);
  }
}

// ---------------- bf16 C = A * B^T GEMM, 128 x BN tile (round-5 engine) -------
// omode: 0 = bf16 out, 1 = fp32 + residual, 2 = fp8 e4m3 out.
template <int BN>
__global__ __launch_bounds__(256) void gemm_abt(
    const ushort_t* __restrict__ A, long long sA, int lda,
    const ushort_t* __restrict__ B, long long sB, int ldb,
    int K, int N, int ldc,
    ushort_t* __restrict__ outB, long long sC,
    const float* __restrict__ bias, int bias_mode, float scale,
    float* __restrict__ outF, const float* __restrict__ resid,
    float* __restrict__ rowsum, const float* __restrict__ colscale,
    int swiz, int omode) {
  constexpr int CPW = (8 + BN / 16) / 4;
  constexpr int SB = (128 + BN) * 32;      // halfwords per LDS buffer
  constexpr int MI = (BN == 128) ? 4 : 2;
  constexpr int NI = 4;
  __shared__ __align__(16) ushort_t Ls[2][SB];

  int bx = blockIdx.x, by = blockIdx.y, bz = blockIdx.z;
  if (swiz) {
    unsigned nx = gridDim.x, ny = gridDim.y;
    unsigned id = (blockIdx.z * ny + blockIdx.y) * nx + blockIdx.x;
    unsigned pb8 = (nx * ny) >> 3;
    unsigned c = id & 7, j = id >> 3;
    bz = j / pb8;
    unsigned jb = j - bz * pb8;
    unsigned jy = jb / nx;
    by = c * (ny >> 3) + jy;
    bx = jb - jy * nx;
  }

  int m0 = by * 128, n0 = bx * BN;
  int t = threadIdx.x;
  int lane = t & 63;
  int quad = lane >> 4, l16 = lane & 15;
  int wave = t >> 6;
  int wm = (BN == 128) ? (wave >> 1) * 64 : wave * 32;
  int wn = (BN == 128) ? (wave & 1) * 64 : 0;

  f32x4 acc[MI][NI];
#pragma unroll
  for (int i = 0; i < MI; i++)
#pragma unroll
    for (int j = 0; j < NI; j++)
#pragma unroll
      for (int r = 0; r < 4; r++) acc[i][j][r] = 0.f;

  const ushort_t* gp[CPW];
  int lofs[CPW];
  int crow = lane >> 2, skoff = (lane & 3) * 8;
#pragma unroll
  for (int i = 0; i < CPW; i++) {
    int c = wave * CPW + i;
    if (c < 8) {
      gp[i] = A + (size_t)bz * sA + (size_t)(m0 + c * 16 + crow) * lda + skoff;
      lofs[i] = c * 1024 + lane * 16;
    } else {
      int slot = (c - 8) * 16 + crow;
      int arow = (slot & ~63) + ((slot & 15) * 4) + ((slot & 63) >> 4);
      gp[i] = B + (size_t)bz * sB + (size_t)(n0 + arow) * ldb + skoff;
      lofs[i] = 8192 + (c - 8) * 1024 + lane * 16;
    }
  }
  char* lbase = (char*)&Ls[0][0];

#pragma unroll
  for (int i = 0; i < CPW; i++) gload16(gp[i], lbase + lofs[i]);

  for (int k0 = 0; k0 < K; k0 += 32) {
    int p = (k0 >> 5) & 1;
    __syncthreads();
    if (k0 + 32 < K) {
      int pofs = (p ^ 1) * (SB * 2);
#pragma unroll
      for (int i = 0; i < CPW; i++) gload16(gp[i] + k0 + 32, lbase + pofs + lofs[i]);
    }
    bf16x8 af[MI], bfr[NI];
#pragma unroll
    for (int i = 0; i < MI; i++)
      af[i] = *(const bf16x8*)&Ls[p][(wm + i * 16 + l16) * 32 + quad * 8];
#pragma unroll
    for (int j = 0; j < NI; j++)
      bfr[j] = *(const bf16x8*)&Ls[p][4096 + (wn + j * 16 + l16) * 32 + quad * 8];
#pragma unroll
    for (int mi = 0; mi < MI; mi++)
#pragma unroll
      for (int ni = 0; ni < NI; ni++)
        acc[mi][ni] = __builtin_amdgcn_mfma_f32_16x16x32_bf16(af[mi], bfr[ni], acc[mi][ni], 0, 0, 0);
  }

  size_t cbase = (size_t)bz * sC;
  int gnb = n0 + wn + l16 * 4;
  float cs4[4] = {1.f, 1.f, 1.f, 1.f};
  if (colscale) {
    float4 c4 = *(const float4*)&colscale[(size_t)bz * N + gnb];
    cs4[0] = 1.f / c4.x; cs4[1] = 1.f / c4.y; cs4[2] = 1.f / c4.z; cs4[3] = 1.f / c4.w;
  }
  float b4[4] = {0.f, 0.f, 0.f, 0.f};
  if (bias_mode == 2) {
    float4 t4 = *(const float4*)&bias[gnb];
    b4[0] = t4.x; b4[1] = t4.y; b4[2] = t4.z; b4[3] = t4.w;
  }
#pragma unroll
  for (int mi = 0; mi < MI; mi++) {
#pragma unroll
    for (int r = 0; r < 4; r++) {
      int m = m0 + wm + mi * 16 + quad * 4 + r;
      float rbias = (bias_mode == 1) ? bias[m] : 0.f;
      float v4[4];
      float rs = 0.f;
#pragma unroll
      for (int ni = 0; ni < NI; ni++) {
        float val = acc[mi][ni][r];
        if (colscale) val *= cs4[ni];
        val += (bias_mode == 2) ? b4[ni] : rbias;
        val *= scale;
        if (rowsum) { val = __expf(val) * 0.0625f; rs += val; }
        v4[ni] = val;
      }
      size_t idx = cbase + (size_t)m * ldc + gnb;
      if (omode == 1) {
        float4 rv = *(const float4*)&resid[idx];
        float4 ov = make_float4(v4[0] + rv.x, v4[1] + rv.y, v4[2] + rv.z, v4[3] + rv.w);
        *(float4*)&outF[idx] = ov;
      } else if (omode == 2) {
        unsigned w = __builtin_amdgcn_cvt_pk_fp8_f32(v4[0], v4[1], 0u, false);
        w = __builtin_amdgcn_cvt_pk_fp8_f32(v4[2], v4[3], w, true);
        *(unsigned*)&((uchar_t*)outB)[idx] = w;
      } else {
        unsigned lo = (unsigned)f2bf(v4[0]) | ((unsigned)f2bf(v4[1]) << 16);
        unsigned hi = (unsigned)f2bf(v4[2]) | ((unsigned)f2bf(v4[3]) << 16);
        *(uint2*)&outB[idx] = make_uint2(lo, hi);
      }
      if (rowsum) {
        rs += __shfl_xor(rs, 1, 64);
        rs += __shfl_xor(rs, 2, 64);
        rs += __shfl_xor(rs, 4, 64);
        rs += __shfl_xor(rs, 8, 64);
        if (l16 == 0) atomicAdd(&rowsum[(size_t)bz * 4096 + m], rs);
      }
    }
  }
}

// ---------------- fp8 C = A * B^T GEMM, 128 x BN tile, BK=32 ------------------
// BK=32 row-major chunk staging: LDS byte o holds (row = o>>5, kbyte = o&31);
// rows 0..127 = A tile, rows 128.. = B tile (column-permuted per 64-row group
// so the epilogue can write 4 consecutive fp8/bf16 columns per lane).
// LDS halves vs BK=64 (16KB / 12KB per wg) -> up to 8-10 wg/CU by LDS.
// NOTE (round 1 post-mortem): do NOT pin min-waves here. __launch_bounds__(256,8)
// capped VGPR at 32 -> acc[4][4] spilled to scratch -> 1.3 GB HBM traffic,
// 5.4x slowdown. Let regalloc take its natural ~60 VGPR.
// omode 0: bf16 out. omode 2: exp(scale*acc)/16 -> fp8 out + rowsum.
template <int BN>
__global__ __launch_bounds__(256) void gemm_fp8(
    const uchar_t* __restrict__ A, long long sA, int lda,
    const uchar_t* __restrict__ B, long long sB, int ldb,
    int K, int ldc,
    void* __restrict__ outp, long long sC,
    float scale, float* __restrict__ rowsum, int swiz, int omode) {
  constexpr int ROWS = 128 + BN;
  constexpr int SBB = ROWS * 32;           // bytes per buffer
  constexpr int NP = (SBB + 4095) / 4096;  // staging passes (256 thr x 16B)
  constexpr bool EXACT = (SBB % 4096) == 0;
  constexpr int MI = (BN == 128) ? 4 : 2;
  constexpr int NI = 4;
  __shared__ __align__(16) uchar_t Ls[2][SBB];

  int bx = blockIdx.x, by = blockIdx.y, bz = blockIdx.z;
  if (swiz) {
    unsigned nx = gridDim.x, ny = gridDim.y;
    unsigned id = (blockIdx.z * ny + blockIdx.y) * nx + blockIdx.x;
    unsigned pb8 = (nx * ny) >> 3;
    unsigned c = id & 7, j = id >> 3;
    bz = j / pb8;
    unsigned jb = j - bz * pb8;
    unsigned jy = jb / nx;
    by = c * (ny >> 3) + jy;
    bx = jb - jy * nx;
  }

  int m0 = by * 128, n0 = bx * BN;
  int t = threadIdx.x;
  int lane = t & 63;
  int quad = lane >> 4, l16 = lane & 15;
  int wave = t >> 6;
  int wm = (BN == 128) ? (wave >> 1) * 64 : wave * 32;
  int wn = (BN == 128) ? (wave & 1) * 64 : 0;

  f32x4 acc[MI][NI];
#pragma unroll
  for (int i = 0; i < MI; i++)
#pragma unroll
    for (int j = 0; j < NI; j++)
#pragma unroll
      for (int r = 0; r < 4; r++) acc[i][j][r] = 0.f;

  // row-major BK=32 staging map: LDS offset o <-> (row o>>5, seg o&16)
  const uchar_t* gp[NP];
  int lofs[NP];
  bool act[NP];
#pragma unroll
  for (int i = 0; i < NP; i++) {
    int o = i * 4096 + t * 16;
    act[i] = EXACT || (o < SBB);
    int oo = act[i] ? o : 0;
    int row = oo >> 5, seg = oo & 16;
    if (row < 128) {
      gp[i] = A + (size_t)bz * sA + (size_t)(m0 + row) * lda + seg;
    } else {
      int br = row - 128;
      int g = br & ~63, loc = br & 63;
      int ar = g + (loc & 15) * 4 + (loc >> 4);
      gp[i] = B + (size_t)bz * sB + (size_t)(n0 + ar) * ldb + seg;
    }
    lofs[i] = oo;
  }
  char* lbase = (char*)&Ls[0][0];

#pragma unroll
  for (int i = 0; i < NP; i++)
    if (act[i]) gload16(gp[i], lbase + lofs[i]);

  int vb = l16 * 32 + quad * 8;
  for (int k0 = 0; k0 < K; k0 += 32) {
    int p = (k0 >> 5) & 1;
    __syncthreads();
    if (k0 + 32 < K) {
      int pofs = (p ^ 1) * SBB;
#pragma unroll
      for (int i = 0; i < NP; i++)
        if (act[i]) gload16(gp[i] + k0 + 32, lbase + pofs + lofs[i]);
    }
    const uchar_t* Lp = &Ls[p][0];
    long long af[MI], bfv[NI];
#pragma unroll
    for (int i = 0; i < MI; i++)
      af[i] = *(const long long*)&Lp[wm * 32 + i * 512 + vb];
#pragma unroll
    for (int j = 0; j < NI; j++)
      bfv[j] = *(const long long*)&Lp[4096 + wn * 32 + j * 512 + vb];
#pragma unroll
    for (int mi = 0; mi < MI; mi++)
#pragma unroll
      for (int ni = 0; ni < NI; ni++)
        acc[mi][ni] = __builtin_amdgcn_mfma_f32_16x16x32_fp8_fp8(af[mi], bfv[ni], acc[mi][ni], 0, 0, 0);
  }

  size_t cbase = (size_t)bz * sC;
  int gnb = n0 + wn + l16 * 4;
#pragma unroll
  for (int mi = 0; mi < MI; mi++) {
#pragma unroll
    for (int r = 0; r < 4; r++) {
      int m = m0 + wm + mi * 16 + quad * 4 + r;
      if (omode == 2) {
        float v4[4];
        float rs = 0.f;
#pragma unroll
        for (int ni = 0; ni < NI; ni++) {
          v4[ni] = __expf(acc[mi][ni][r] * scale) * 0.0625f;
          rs += v4[ni];
        }
        unsigned w = __builtin_amdgcn_cvt_pk_fp8_f32(v4[0], v4[1], 0u, false);
        w = __builtin_amdgcn_cvt_pk_fp8_f32(v4[2], v4[3], w, true);
        *(unsigned*)&((uchar_t*)outp)[cbase + (size_t)m * ldc + gnb] = w;
        rs += __shfl_xor(rs, 1, 64);
        rs += __shfl_xor(rs, 2, 64);
        rs += __shfl_xor(rs, 4, 64);
        rs += __shfl_xor(rs, 8, 64);
        if (l16 == 0) atomicAdd(&rowsum[(size_t)bz * 4096 + m], rs);
      } else {
        unsigned lo = (unsigned)f2bf(acc[mi][0][r]) | ((unsigned)f2bf(acc[mi][1][r]) << 16);
        unsigned hi = (unsigned)f2bf(acc[mi][2][r]) | ((unsigned)f2bf(acc[mi][3][r]) << 16);
        *(uint2*)&((ushort_t*)outp)[cbase + (size_t)m * ldc + gnb] = make_uint2(lo, hi);
      }
    }
  }
}

extern "C" void kernel_launch(void* const* d_in, const int* in_sizes, int n_in,
                              void* d_out, int out_size, void* d_ws, size_t ws_size,
                              hipStream_t stream) {
  const float* x     = (const float*)d_in[0];
  const float* gamma = (const float*)d_in[1];
  const float* beta  = (const float*)d_in[2];
  const float* wq    = (const float*)d_in[3];
  const float* bq    = (const float*)d_in[4];
  const float* wk    = (const float*)d_in[5];
  const float* bk    = (const float*)d_in[6];
  const float* wv    = (const float*)d_in[7];
  const float* bv    = (const float*)d_in[8];
  const float* wo    = (const float*)d_in[9];
  const float* bo    = (const float*)d_in[10];
  float* out = (float*)d_out;

  // workspace layout
  ushort_t* wb  = (ushort_t*)d_ws;     // [wq;wk] 1024x512, wv, wo (bf16)
  ushort_t* wvb = wb + 524288;
  ushort_t* wob = wb + 786432;
  ushort_t* hnT = wb + 1048576;        // 2 x 4096 x 512 bf16
  uchar_t*  qk8 = (uchar_t*)(hnT + 4194304);  // 2 x 4096 x 1024 fp8 (q | k)
  uchar_t*  vC8 = qk8 + 8388608;       // 2 x 512 x 4096 fp8
  ushort_t* OT  = (ushort_t*)(vC8 + 4194304); // 2 x 4096 x 512 bf16
  uchar_t*  S8  = (uchar_t*)(OT + 4194304);   // 2 x 4096 x 4096 fp8 (P' = exp/16)
  float* fbuf   = (float*)(S8 + 33554432);
  float* stats  = fbuf;                // 128
  float* stats2 = fbuf + 128;          // 128
  float* qkbias = fbuf + 256;          // 1024
  float* l      = (float*)hnT;         // 2 x 4096 row sums (hnT dead after v-GEMM)

  const long long HS = 2097152;   // 4096*512 per batch
  const long long QS = 4194304;   // 4096*1024 per batch (bytes, fp8)
  const long long SS = 16777216;  // 4096*4096 per batch (bytes, fp8)
  const float scale = 0.044194173824159216f;  // 512^-0.5

  cvt_weights<<<dim3(1029), dim3(256), 0, stream>>>(wq, wk, wv, wo, bq, bk, wb, qkbias, stats2);
  gn_stats_partial<<<dim3(256), dim3(256), 0, stream>>>(x, stats2);
  gn_finalize<<<dim3(1), dim3(64), 0, stream>>>(stats2, stats);
  gn_apply<<<dim3(128, 16, 2), dim3(32, 8), 0, stream>>>(x, gamma, beta, stats, hnT);
  // qk8 = hnT * [wq;wk]^T (M=4096, N=1024, K=512), packed col bias, fp8 out, unscaled
  gemm_abt<128><<<dim3(8, 32, 2), dim3(256), 0, stream>>>(
      hnT, HS, 512, wb, 0, 512, 512, 1024, 1024, (ushort_t*)qk8, QS, qkbias, 2, 1.f,
      nullptr, nullptr, nullptr, nullptr, 1, 2);
  // vC8 = wv * hnT^T (M=512, N=4096, K=512), row bias, fp8 out
  gemm_abt<64><<<dim3(64, 4, 2), dim3(256), 0, stream>>>(
      wvb, 0, 512, hnT, HS, 512, 512, 4096, 4096, (ushort_t*)vC8, HS, bv, 1, 1.f,
      nullptr, nullptr, nullptr, nullptr, 0, 2);
  // hnT dead; reuse as rowsum l
  zero_f32<<<dim3(32), dim3(256), 0, stream>>>(l);
  // P' = exp(scale * q*k^T)/16 fp8 + fused row sums (fp8 MFMA, M=N=4096, K=512)
  gemm_fp8<128><<<dim3(32, 32, 2), dim3(256), 0, stream>>>(
      qk8, QS, 1024, qk8 + 512, QS, 1024, 512, 4096, S8, SS, scale, l, 1, 2);
  // OT = P' * vC8^T (fp8 MFMA, M=4096, N=512, K=4096), bf16 out, swizzled
  gemm_fp8<64><<<dim3(8, 32, 2), dim3(256), 0, stream>>>(
      S8, SS, 4096, vC8, HS, 4096, 4096, 512, OT, HS, 1.f, nullptr, 1, 0);
  // y = wo * (OT/l')^T + bo + x (M=512, N=4096, K=512), fp32 + residual
  gemm_abt<64><<<dim3(64, 4, 2), dim3(256), 0, stream>>>(
      wob, 0, 512, OT, HS, 512, 512, 4096, 4096, nullptr, HS, bo, 1, 1.f,
      out, x, nullptr, l, 0, 1);
}

// Round 3
// 225.798 us; speedup vs baseline: 2.1599x; 1.1066x over previous
//
#include <hip/hip_runtime.h>

typedef unsigned short ushort_t;
typedef unsigned char uchar_t;
typedef __bf16 bf16x8 __attribute__((ext_vector_type(8)));
typedef float f32x4 __attribute__((ext_vector_type(4)));

__device__ __forceinline__ ushort_t f2bf(float f) {
  unsigned u = __float_as_uint(f);
  u += 0x7fff + ((u >> 16) & 1);
  return (ushort_t)(u >> 16);
}

__device__ __forceinline__ void gload16(const void* g, void* l) {
  __builtin_amdgcn_global_load_lds(
      (const __attribute__((address_space(1))) unsigned int*)g,
      (__attribute__((address_space(3))) unsigned int*)l, 16, 0, 0);
}

// ---------------- weight fp32 -> bf16, pack qk bias, zero stats2 ----------------
__global__ __launch_bounds__(256) void cvt_weights(
    const float* __restrict__ wq, const float* __restrict__ wk,
    const float* __restrict__ wv, const float* __restrict__ wo,
    const float* __restrict__ bq, const float* __restrict__ bk,
    ushort_t* __restrict__ dst, float* __restrict__ qkbias,
    float* __restrict__ stats2) {
  int b = blockIdx.x, t = threadIdx.x;
  if (b < 1024) {
    int i = b * 256 + t;
    dst[i]          = f2bf(wq[i]);
    dst[262144 + i] = f2bf(wk[i]);
    dst[524288 + i] = f2bf(wv[i]);
    dst[786432 + i] = f2bf(wo[i]);
  } else if (b < 1028) {
    int j = (b - 1024) * 256 + t;  // 0..1023
    qkbias[j] = (j < 512) ? bq[j] : bk[j - 512];
  } else {
    if (t < 128) stats2[t] = 0.f;
  }
}

// ---------------- zero the rowsum accumulator ----------------
__global__ __launch_bounds__(256) void zero_f32(float* __restrict__ p) {
  p[blockIdx.x * 256 + threadIdx.x] = 0.f;
}

// ---------------- group norm partial stats: 4 blocks per (b,g) ----------------
__global__ __launch_bounds__(256) void gn_stats_partial(const float* __restrict__ x,
                                                        float* __restrict__ stats2) {
  int bg = blockIdx.x >> 2, q = blockIdx.x & 3;
  const float4* p = (const float4*)(x + (size_t)bg * 65536 + q * 16384);
  float s = 0.f, ss = 0.f;
  for (int i = threadIdx.x; i < 4096; i += 256) {
    float4 v = p[i];
    s += v.x + v.y + v.z + v.w;
    ss += v.x * v.x + v.y * v.y + v.z * v.z + v.w * v.w;
  }
  for (int off = 32; off; off >>= 1) {
    s += __shfl_xor(s, off, 64);
    ss += __shfl_xor(ss, off, 64);
  }
  __shared__ float sh[8];
  int wave = threadIdx.x >> 6, lane = threadIdx.x & 63;
  if (lane == 0) { sh[wave] = s; sh[4 + wave] = ss; }
  __syncthreads();
  if (threadIdx.x == 0) {
    atomicAdd(&stats2[bg * 2], sh[0] + sh[1] + sh[2] + sh[3]);
    atomicAdd(&stats2[bg * 2 + 1], sh[4] + sh[5] + sh[6] + sh[7]);
  }
}

__global__ __launch_bounds__(64) void gn_finalize(const float* __restrict__ stats2,
                                                  float* __restrict__ stats) {
  int t = threadIdx.x;  // 64 groups total (2 batches x 32)
  float s = stats2[t * 2], ss = stats2[t * 2 + 1];
  float mean = s * (1.f / 65536.f);
  float var = ss * (1.f / 65536.f) - mean * mean;
  stats[t * 2] = mean;
  stats[t * 2 + 1] = rsqrtf(var + 1e-6f);
}

// ---------------- GN apply + transpose: x (b,c,n) -> hnT (b,n,c) bf16 ----------------
__global__ __launch_bounds__(256) void gn_apply(
    const float* __restrict__ x, const float* __restrict__ gamma,
    const float* __restrict__ beta, const float* __restrict__ stats,
    ushort_t* __restrict__ hnT) {
  __shared__ float T[32][33];
  int i0 = blockIdx.x * 32, c0 = blockIdx.y * 32, b = blockIdx.z;
  int tx = threadIdx.x, ty = threadIdx.y;  // (32,8)
#pragma unroll
  for (int k = 0; k < 4; k++) {
    int cl = ty + k * 8;
    int c = c0 + cl;
    int bg = (b * 32 + (c >> 4)) * 2;
    float mean = stats[bg], rstd = stats[bg + 1];
    float v = x[((size_t)(b * 512 + c)) * 4096 + i0 + tx];
    T[cl][tx] = (v - mean) * rstd * gamma[c] + beta[c];
  }
  __syncthreads();
#pragma unroll
  for (int k = 0; k < 4; k++) {
    int il = ty + k * 8;
    hnT[((size_t)b * 4096 + i0 + il) * 512 + c0 + tx] = f2bf(T[tx][il]);
  }
}

// ---------------- bf16 C = A * B^T GEMM, 128 x BN tile (round-5 engine) -------
// omode: 0 = bf16 out, 1 = fp32 + residual, 2 = fp8 e4m3 out.
template <int BN>
__global__ __launch_bounds__(256) void gemm_abt(
    const ushort_t* __restrict__ A, long long sA, int lda,
    const ushort_t* __restrict__ B, long long sB, int ldb,
    int K, int N, int ldc,
    ushort_t* __restrict__ outB, long long sC,
    const float* __restrict__ bias, int bias_mode, float scale,
    float* __restrict__ outF, const float* __restrict__ resid,
    float* __restrict__ rowsum, const float* __restrict__ colscale,
    int swiz, int omode) {
  constexpr int CPW = (8 + BN / 16) / 4;
  constexpr int SB = (128 + BN) * 32;      // halfwords per LDS buffer
  constexpr int MI = (BN == 128) ? 4 : 2;
  constexpr int NI = 4;
  __shared__ __align__(16) ushort_t Ls[2][SB];

  int bx = blockIdx.x, by = blockIdx.y, bz = blockIdx.z;
  if (swiz) {
    unsigned nx = gridDim.x, ny = gridDim.y;
    unsigned id = (blockIdx.z * ny + blockIdx.y) * nx + blockIdx.x;
    unsigned pb8 = (nx * ny) >> 3;
    unsigned c = id & 7, j = id >> 3;
    bz = j / pb8;
    unsigned jb = j - bz * pb8;
    unsigned jy = jb / nx;
    by = c * (ny >> 3) + jy;
    bx = jb - jy * nx;
  }

  int m0 = by * 128, n0 = bx * BN;
  int t = threadIdx.x;
  int lane = t & 63;
  int quad = lane >> 4, l16 = lane & 15;
  int wave = t >> 6;
  int wm = (BN == 128) ? (wave >> 1) * 64 : wave * 32;
  int wn = (BN == 128) ? (wave & 1) * 64 : 0;

  f32x4 acc[MI][NI];
#pragma unroll
  for (int i = 0; i < MI; i++)
#pragma unroll
    for (int j = 0; j < NI; j++)
#pragma unroll
      for (int r = 0; r < 4; r++) acc[i][j][r] = 0.f;

  const ushort_t* gp[CPW];
  int lofs[CPW];
  int crow = lane >> 2, skoff = (lane & 3) * 8;
#pragma unroll
  for (int i = 0; i < CPW; i++) {
    int c = wave * CPW + i;
    if (c < 8) {
      gp[i] = A + (size_t)bz * sA + (size_t)(m0 + c * 16 + crow) * lda + skoff;
      lofs[i] = c * 1024 + lane * 16;
    } else {
      int slot = (c - 8) * 16 + crow;
      int arow = (slot & ~63) + ((slot & 15) * 4) + ((slot & 63) >> 4);
      gp[i] = B + (size_t)bz * sB + (size_t)(n0 + arow) * ldb + skoff;
      lofs[i] = 8192 + (c - 8) * 1024 + lane * 16;
    }
  }
  char* lbase = (char*)&Ls[0][0];

#pragma unroll
  for (int i = 0; i < CPW; i++) gload16(gp[i], lbase + lofs[i]);

  for (int k0 = 0; k0 < K; k0 += 32) {
    int p = (k0 >> 5) & 1;
    __syncthreads();
    if (k0 + 32 < K) {
      int pofs = (p ^ 1) * (SB * 2);
#pragma unroll
      for (int i = 0; i < CPW; i++) gload16(gp[i] + k0 + 32, lbase + pofs + lofs[i]);
    }
    bf16x8 af[MI], bfr[NI];
#pragma unroll
    for (int i = 0; i < MI; i++)
      af[i] = *(const bf16x8*)&Ls[p][(wm + i * 16 + l16) * 32 + quad * 8];
#pragma unroll
    for (int j = 0; j < NI; j++)
      bfr[j] = *(const bf16x8*)&Ls[p][4096 + (wn + j * 16 + l16) * 32 + quad * 8];
#pragma unroll
    for (int mi = 0; mi < MI; mi++)
#pragma unroll
      for (int ni = 0; ni < NI; ni++)
        acc[mi][ni] = __builtin_amdgcn_mfma_f32_16x16x32_bf16(af[mi], bfr[ni], acc[mi][ni], 0, 0, 0);
  }

  size_t cbase = (size_t)bz * sC;
  int gnb = n0 + wn + l16 * 4;
  float cs4[4] = {1.f, 1.f, 1.f, 1.f};
  if (colscale) {
    float4 c4 = *(const float4*)&colscale[(size_t)bz * N + gnb];
    cs4[0] = 1.f / c4.x; cs4[1] = 1.f / c4.y; cs4[2] = 1.f / c4.z; cs4[3] = 1.f / c4.w;
  }
  float b4[4] = {0.f, 0.f, 0.f, 0.f};
  if (bias_mode == 2) {
    float4 t4 = *(const float4*)&bias[gnb];
    b4[0] = t4.x; b4[1] = t4.y; b4[2] = t4.z; b4[3] = t4.w;
  }
#pragma unroll
  for (int mi = 0; mi < MI; mi++) {
#pragma unroll
    for (int r = 0; r < 4; r++) {
      int m = m0 + wm + mi * 16 + quad * 4 + r;
      float rbias = (bias_mode == 1) ? bias[m] : 0.f;
      float v4[4];
      float rs = 0.f;
#pragma unroll
      for (int ni = 0; ni < NI; ni++) {
        float val = acc[mi][ni][r];
        if (colscale) val *= cs4[ni];
        val += (bias_mode == 2) ? b4[ni] : rbias;
        val *= scale;
        if (rowsum) { val = __expf(val) * 0.0625f; rs += val; }
        v4[ni] = val;
      }
      size_t idx = cbase + (size_t)m * ldc + gnb;
      if (omode == 1) {
        float4 rv = *(const float4*)&resid[idx];
        float4 ov = make_float4(v4[0] + rv.x, v4[1] + rv.y, v4[2] + rv.z, v4[3] + rv.w);
        *(float4*)&outF[idx] = ov;
      } else if (omode == 2) {
        unsigned w = __builtin_amdgcn_cvt_pk_fp8_f32(v4[0], v4[1], 0u, false);
        w = __builtin_amdgcn_cvt_pk_fp8_f32(v4[2], v4[3], w, true);
        *(unsigned*)&((uchar_t*)outB)[idx] = w;
      } else {
        unsigned lo = (unsigned)f2bf(v4[0]) | ((unsigned)f2bf(v4[1]) << 16);
        unsigned hi = (unsigned)f2bf(v4[2]) | ((unsigned)f2bf(v4[3]) << 16);
        *(uint2*)&outB[idx] = make_uint2(lo, hi);
      }
      if (rowsum) {
        rs += __shfl_xor(rs, 1, 64);
        rs += __shfl_xor(rs, 2, 64);
        rs += __shfl_xor(rs, 4, 64);
        rs += __shfl_xor(rs, 8, 64);
        if (l16 == 0) atomicAdd(&rowsum[(size_t)bz * 4096 + m], rs);
      }
    }
  }
}

// ---------------- fp8 C = A * B^T GEMM, 128 x BN tile, BKB in {32,128} -------
// BKB is the K-bytes per LDS tile, chosen per launch regime:
//  * BKB=32 (QK, grid 8 wg/CU): small LDS (16KB dbuf) -> high occupancy, TLP
//    hides the per-iter staging drain. Row-major map: byte o = (row o>>5,
//    kb o&31); BK=32 row stride (8 dwords) already spreads banks.
//  * BKB=128 (PV, grid-limited 2 wg/CU): occupancy can't hide latency, so
//    amortize it: 4x fewer iterations/barriers. Row stride 128B = 32 dwords
//    would be a 32-way bank conflict, so XOR-swizzle kb ^= ((row&7)<<4)
//    applied on BOTH the staging source address and the fragment read
//    address (rule #21 involution; 8B reads stay inside 16B granules).
// B rows are column-permuted per 64-row group (staging side) so the epilogue
// writes 4 consecutive columns per lane — same perm for both BKB.
// NOTE (round 1): no min-waves pin — (256,8) forced VGPR=32, spilled acc,
// 1.3GB scratch traffic. NOTE (round 2): BK=32 for the 512-wg PV doubled
// exposed latency (1190 cyc/iter) -> 63us. BK is a per-regime knob.
// omode 0: bf16 out. omode 2: exp(scale*acc)/16 -> fp8 out + rowsum.
template <int BN, int BKB>
__global__ __launch_bounds__(256) void gemm_fp8(
    const uchar_t* __restrict__ A, long long sA, int lda,
    const uchar_t* __restrict__ B, long long sB, int ldb,
    int K, int ldc,
    void* __restrict__ outp, long long sC,
    float scale, float* __restrict__ rowsum, int swiz, int omode) {
  constexpr int ROWS = 128 + BN;
  constexpr int SBB = ROWS * BKB;          // bytes per buffer
  constexpr int NP = (SBB + 4095) / 4096;  // staging passes (256 thr x 16B)
  constexpr bool EXACT = (SBB % 4096) == 0;
  constexpr int BASEB = 128 * BKB;         // B-region byte offset in LDS
  constexpr int MI = (BN == 128) ? 4 : 2;
  constexpr int NI = 4;
  __shared__ __align__(16) uchar_t Ls[2][SBB];

  int bx = blockIdx.x, by = blockIdx.y, bz = blockIdx.z;
  if (swiz) {
    unsigned nx = gridDim.x, ny = gridDim.y;
    unsigned id = (blockIdx.z * ny + blockIdx.y) * nx + blockIdx.x;
    unsigned pb8 = (nx * ny) >> 3;
    unsigned c = id & 7, j = id >> 3;
    bz = j / pb8;
    unsigned jb = j - bz * pb8;
    unsigned jy = jb / nx;
    by = c * (ny >> 3) + jy;
    bx = jb - jy * nx;
  }

  int m0 = by * 128, n0 = bx * BN;
  int t = threadIdx.x;
  int lane = t & 63;
  int quad = lane >> 4, l16 = lane & 15;
  int wave = t >> 6;
  int wm = (BN == 128) ? (wave >> 1) * 64 : wave * 32;
  int wn = (BN == 128) ? (wave & 1) * 64 : 0;

  f32x4 acc[MI][NI];
#pragma unroll
  for (int i = 0; i < MI; i++)
#pragma unroll
    for (int j = 0; j < NI; j++)
#pragma unroll
      for (int r = 0; r < 4; r++) acc[i][j][r] = 0.f;

  // staging map: LDS 16B slot o -> (row, kb) with per-BKB swizzle
  const uchar_t* gp[NP];
  int lofs[NP];
  bool act[NP];
#pragma unroll
  for (int i = 0; i < NP; i++) {
    int o = i * 4096 + t * 16;
    act[i] = EXACT || (o < SBB);
    int oo = act[i] ? o : 0;
    int row, kb;
    if constexpr (BKB == 32) {
      row = oo >> 5; kb = oo & 31;
    } else {
      row = oo >> 7;
      kb = (oo & 127) ^ ((row & 7) << 4);
    }
    if (row < 128) {
      gp[i] = A + (size_t)bz * sA + (size_t)(m0 + row) * lda + kb;
    } else {
      int br = row - 128;
      int g = br & ~63, loc = br & 63;
      int ar = g + (loc & 15) * 4 + (loc >> 4);
      gp[i] = B + (size_t)bz * sB + (size_t)(n0 + ar) * ldb + kb;
    }
    lofs[i] = oo;
  }
  char* lbase = (char*)&Ls[0][0];

#pragma unroll
  for (int i = 0; i < NP; i++)
    if (act[i]) gload16(gp[i], lbase + lofs[i]);

  for (int k0 = 0; k0 < K; k0 += BKB) {
    int p = (k0 / BKB) & 1;
    __syncthreads();
    if (k0 + BKB < K) {
      int pofs = (p ^ 1) * SBB;
#pragma unroll
      for (int i = 0; i < NP; i++)
        if (act[i]) gload16(gp[i] + k0 + BKB, lbase + pofs + lofs[i]);
    }
    const uchar_t* Lp = &Ls[p][0];
    if constexpr (BKB == 32) {
      int vb = l16 * 32 + quad * 8;
      long long af[MI], bfv[NI];
#pragma unroll
      for (int i = 0; i < MI; i++)
        af[i] = *(const long long*)&Lp[wm * 32 + i * 512 + vb];
#pragma unroll
      for (int j = 0; j < NI; j++)
        bfv[j] = *(const long long*)&Lp[BASEB + wn * 32 + j * 512 + vb];
#pragma unroll
      for (int mi = 0; mi < MI; mi++)
#pragma unroll
        for (int ni = 0; ni < NI; ni++)
          acc[mi][ni] = __builtin_amdgcn_mfma_f32_16x16x32_fp8_fp8(af[mi], bfv[ni], acc[mi][ni], 0, 0, 0);
    } else {
      int swz = (l16 & 7) << 4;
#pragma unroll
      for (int ks = 0; ks < 4; ks++) {
        int kx = (ks * 32 + quad * 8) ^ swz;
        long long af[MI], bfv[NI];
#pragma unroll
        for (int i = 0; i < MI; i++)
          af[i] = *(const long long*)&Lp[(wm + i * 16 + l16) * 128 + kx];
#pragma unroll
        for (int j = 0; j < NI; j++)
          bfv[j] = *(const long long*)&Lp[BASEB + (wn + j * 16 + l16) * 128 + kx];
#pragma unroll
        for (int mi = 0; mi < MI; mi++)
#pragma unroll
          for (int ni = 0; ni < NI; ni++)
            acc[mi][ni] = __builtin_amdgcn_mfma_f32_16x16x32_fp8_fp8(af[mi], bfv[ni], acc[mi][ni], 0, 0, 0);
      }
    }
  }

  size_t cbase = (size_t)bz * sC;
  int gnb = n0 + wn + l16 * 4;
#pragma unroll
  for (int mi = 0; mi < MI; mi++) {
#pragma unroll
    for (int r = 0; r < 4; r++) {
      int m = m0 + wm + mi * 16 + quad * 4 + r;
      if (omode == 2) {
        float v4[4];
        float rs = 0.f;
#pragma unroll
        for (int ni = 0; ni < NI; ni++) {
          v4[ni] = __expf(acc[mi][ni][r] * scale) * 0.0625f;
          rs += v4[ni];
        }
        unsigned w = __builtin_amdgcn_cvt_pk_fp8_f32(v4[0], v4[1], 0u, false);
        w = __builtin_amdgcn_cvt_pk_fp8_f32(v4[2], v4[3], w, true);
        *(unsigned*)&((uchar_t*)outp)[cbase + (size_t)m * ldc + gnb] = w;
        rs += __shfl_xor(rs, 1, 64);
        rs += __shfl_xor(rs, 2, 64);
        rs += __shfl_xor(rs, 4, 64);
        rs += __shfl_xor(rs, 8, 64);
        if (l16 == 0) atomicAdd(&rowsum[(size_t)bz * 4096 + m], rs);
      } else {
        unsigned lo = (unsigned)f2bf(acc[mi][0][r]) | ((unsigned)f2bf(acc[mi][1][r]) << 16);
        unsigned hi = (unsigned)f2bf(acc[mi][2][r]) | ((unsigned)f2bf(acc[mi][3][r]) << 16);
        *(uint2*)&((ushort_t*)outp)[cbase + (size_t)m * ldc + gnb] = make_uint2(lo, hi);
      }
    }
  }
}

extern "C" void kernel_launch(void* const* d_in, const int* in_sizes, int n_in,
                              void* d_out, int out_size, void* d_ws, size_t ws_size,
                              hipStream_t stream) {
  const float* x     = (const float*)d_in[0];
  const float* gamma = (const float*)d_in[1];
  const float* beta  = (const float*)d_in[2];
  const float* wq    = (const float*)d_in[3];
  const float* bq    = (const float*)d_in[4];
  const float* wk    = (const float*)d_in[5];
  const float* bk    = (const float*)d_in[6];
  const float* wv    = (const float*)d_in[7];
  const float* bv    = (const float*)d_in[8];
  const float* wo    = (const float*)d_in[9];
  const float* bo    = (const float*)d_in[10];
  float* out = (float*)d_out;

  // workspace layout
  ushort_t* wb  = (ushort_t*)d_ws;     // [wq;wk] 1024x512, wv, wo (bf16)
  ushort_t* wvb = wb + 524288;
  ushort_t* wob = wb + 786432;
  ushort_t* hnT = wb + 1048576;        // 2 x 4096 x 512 bf16
  uchar_t*  qk8 = (uchar_t*)(hnT + 4194304);  // 2 x 4096 x 1024 fp8 (q | k)
  uchar_t*  vC8 = qk8 + 8388608;       // 2 x 512 x 4096 fp8
  ushort_t* OT  = (ushort_t*)(vC8 + 4194304); // 2 x 4096 x 512 bf16
  uchar_t*  S8  = (uchar_t*)(OT + 4194304);   // 2 x 4096 x 4096 fp8 (P' = exp/16)
  float* fbuf   = (float*)(S8 + 33554432);
  float* stats  = fbuf;                // 128
  float* stats2 = fbuf + 128;          // 128
  float* qkbias = fbuf + 256;          // 1024
  float* l      = (float*)hnT;         // 2 x 4096 row sums (hnT dead after v-GEMM)

  const long long HS = 2097152;   // 4096*512 per batch
  const long long QS = 4194304;   // 4096*1024 per batch (bytes, fp8)
  const long long SS = 16777216;  // 4096*4096 per batch (bytes, fp8)
  const float scale = 0.044194173824159216f;  // 512^-0.5

  cvt_weights<<<dim3(1029), dim3(256), 0, stream>>>(wq, wk, wv, wo, bq, bk, wb, qkbias, stats2);
  gn_stats_partial<<<dim3(256), dim3(256), 0, stream>>>(x, stats2);
  gn_finalize<<<dim3(1), dim3(64), 0, stream>>>(stats2, stats);
  gn_apply<<<dim3(128, 16, 2), dim3(32, 8), 0, stream>>>(x, gamma, beta, stats, hnT);
  // qk8 = hnT * [wq;wk]^T (M=4096, N=1024, K=512), packed col bias, fp8 out, unscaled
  gemm_abt<128><<<dim3(8, 32, 2), dim3(256), 0, stream>>>(
      hnT, HS, 512, wb, 0, 512, 512, 1024, 1024, (ushort_t*)qk8, QS, qkbias, 2, 1.f,
      nullptr, nullptr, nullptr, nullptr, 1, 2);
  // vC8 = wv * hnT^T (M=512, N=4096, K=512), row bias, fp8 out
  gemm_abt<64><<<dim3(64, 4, 2), dim3(256), 0, stream>>>(
      wvb, 0, 512, hnT, HS, 512, 512, 4096, 4096, (ushort_t*)vC8, HS, bv, 1, 1.f,
      nullptr, nullptr, nullptr, nullptr, 0, 2);
  // hnT dead; reuse as rowsum l
  zero_f32<<<dim3(32), dim3(256), 0, stream>>>(l);
  // P' = exp(scale * q*k^T)/16 fp8 + fused row sums (fp8 MFMA, M=N=4096, K=512)
  // BK=32: 2048 wg = 8 wg/CU, small LDS -> TLP regime
  gemm_fp8<128, 32><<<dim3(32, 32, 2), dim3(256), 0, stream>>>(
      qk8, QS, 1024, qk8 + 512, QS, 1024, 512, 4096, S8, SS, scale, l, 1, 2);
  // OT = P' * vC8^T (fp8 MFMA, M=4096, N=512, K=4096), bf16 out, swizzled
  // BK=128: 512 wg = 2 wg/CU grid-limited -> amortize exposed latency
  gemm_fp8<64, 128><<<dim3(8, 32, 2), dim3(256), 0, stream>>>(
      S8, SS, 4096, vC8, HS, 4096, 4096, 512, OT, HS, 1.f, nullptr, 1, 0);
  // y = wo * (OT/l')^T + bo + x (M=512, N=4096, K=512), fp32 + residual
  gemm_abt<64><<<dim3(64, 4, 2), dim3(256), 0, stream>>>(
      wob, 0, 512, OT, HS, 512, 512, 4096, 4096, nullptr, HS, bo, 1, 1.f,
      out, x, nullptr, l, 0, 1);
}

// Round 4
// 222.185 us; speedup vs baseline: 2.1950x; 1.0163x over previous
//
#include <hip/hip_runtime.h>

typedef unsigned short ushort_t;
typedef unsigned char uchar_t;
typedef __bf16 bf16x8 __attribute__((ext_vector_type(8)));
typedef float f32x4 __attribute__((ext_vector_type(4)));

__device__ __forceinline__ ushort_t f2bf(float f) {
  unsigned u = __float_as_uint(f);
  u += 0x7fff + ((u >> 16) & 1);
  return (ushort_t)(u >> 16);
}

__device__ __forceinline__ void gload16(const void* g, void* l) {
  __builtin_amdgcn_global_load_lds(
      (const __attribute__((address_space(1))) unsigned int*)g,
      (__attribute__((address_space(3))) unsigned int*)l, 16, 0, 0);
}

// ---------------- weight fp32 -> bf16, pack qk bias, zero stats2 ----------------
__global__ __launch_bounds__(256) void cvt_weights(
    const float* __restrict__ wq, const float* __restrict__ wk,
    const float* __restrict__ wv, const float* __restrict__ wo,
    const float* __restrict__ bq, const float* __restrict__ bk,
    ushort_t* __restrict__ dst, float* __restrict__ qkbias,
    float* __restrict__ stats2) {
  int b = blockIdx.x, t = threadIdx.x;
  if (b < 1024) {
    int i = b * 256 + t;
    dst[i]          = f2bf(wq[i]);
    dst[262144 + i] = f2bf(wk[i]);
    dst[524288 + i] = f2bf(wv[i]);
    dst[786432 + i] = f2bf(wo[i]);
  } else if (b < 1028) {
    int j = (b - 1024) * 256 + t;  // 0..1023
    qkbias[j] = (j < 512) ? bq[j] : bk[j - 512];
  } else {
    if (t < 128) stats2[t] = 0.f;
  }
}

// ---------------- zero the rowsum accumulator ----------------
__global__ __launch_bounds__(256) void zero_f32(float* __restrict__ p) {
  p[blockIdx.x * 256 + threadIdx.x] = 0.f;
}

// ---------------- group norm partial stats: 4 blocks per (b,g) ----------------
__global__ __launch_bounds__(256) void gn_stats_partial(const float* __restrict__ x,
                                                        float* __restrict__ stats2) {
  int bg = blockIdx.x >> 2, q = blockIdx.x & 3;
  const float4* p = (const float4*)(x + (size_t)bg * 65536 + q * 16384);
  float s = 0.f, ss = 0.f;
  for (int i = threadIdx.x; i < 4096; i += 256) {
    float4 v = p[i];
    s += v.x + v.y + v.z + v.w;
    ss += v.x * v.x + v.y * v.y + v.z * v.z + v.w * v.w;
  }
  for (int off = 32; off; off >>= 1) {
    s += __shfl_xor(s, off, 64);
    ss += __shfl_xor(ss, off, 64);
  }
  __shared__ float sh[8];
  int wave = threadIdx.x >> 6, lane = threadIdx.x & 63;
  if (lane == 0) { sh[wave] = s; sh[4 + wave] = ss; }
  __syncthreads();
  if (threadIdx.x == 0) {
    atomicAdd(&stats2[bg * 2], sh[0] + sh[1] + sh[2] + sh[3]);
    atomicAdd(&stats2[bg * 2 + 1], sh[4] + sh[5] + sh[6] + sh[7]);
  }
}

__global__ __launch_bounds__(64) void gn_finalize(const float* __restrict__ stats2,
                                                  float* __restrict__ stats) {
  int t = threadIdx.x;  // 64 groups total (2 batches x 32)
  float s = stats2[t * 2], ss = stats2[t * 2 + 1];
  float mean = s * (1.f / 65536.f);
  float var = ss * (1.f / 65536.f) - mean * mean;
  stats[t * 2] = mean;
  stats[t * 2 + 1] = rsqrtf(var + 1e-6f);
}

// ---------------- GN apply + transpose: x (b,c,n) -> hnT (b,n,c) bf16 ----------------
__global__ __launch_bounds__(256) void gn_apply(
    const float* __restrict__ x, const float* __restrict__ gamma,
    const float* __restrict__ beta, const float* __restrict__ stats,
    ushort_t* __restrict__ hnT) {
  __shared__ float T[32][33];
  int i0 = blockIdx.x * 32, c0 = blockIdx.y * 32, b = blockIdx.z;
  int tx = threadIdx.x, ty = threadIdx.y;  // (32,8)
#pragma unroll
  for (int k = 0; k < 4; k++) {
    int cl = ty + k * 8;
    int c = c0 + cl;
    int bg = (b * 32 + (c >> 4)) * 2;
    float mean = stats[bg], rstd = stats[bg + 1];
    float v = x[((size_t)(b * 512 + c)) * 4096 + i0 + tx];
    T[cl][tx] = (v - mean) * rstd * gamma[c] + beta[c];
  }
  __syncthreads();
#pragma unroll
  for (int k = 0; k < 4; k++) {
    int il = ty + k * 8;
    hnT[((size_t)b * 4096 + i0 + il) * 512 + c0 + tx] = f2bf(T[tx][il]);
  }
}

// ---------------- bf16 C = A * B^T GEMM, 128 x BN tile, UNR k-chunks/buffer --
// UNR: number of 32-elem K-chunks staged per LDS buffer (K-step = 32*UNR).
// UNR=2 for the 512-wg (2 wg/CU, grid-limited) launches: halves the
// barrier+drain count per round-2's measurement (~1190 exposed cyc/iter when
// occupancy can't hide the staging latency). LDS: BN=128 -> 64KB, BN=64 -> 48KB
// (fine: these launches are grid-capped at 2 wg/CU regardless).
// omode: 0 = bf16 out, 1 = fp32 + residual, 2 = fp8 e4m3 out.
template <int BN, int UNR>
__global__ __launch_bounds__(256) void gemm_abt(
    const ushort_t* __restrict__ A, long long sA, int lda,
    const ushort_t* __restrict__ B, long long sB, int ldb,
    int K, int N, int ldc,
    ushort_t* __restrict__ outB, long long sC,
    const float* __restrict__ bias, int bias_mode, float scale,
    float* __restrict__ outF, const float* __restrict__ resid,
    float* __restrict__ rowsum, const float* __restrict__ colscale,
    int swiz, int omode) {
  constexpr int CPW = (8 + BN / 16) / 4;
  constexpr int SB = (128 + BN) * 32;      // halfwords per 32-elem k-chunk
  constexpr int STEP = 32 * UNR;
  constexpr int MI = (BN == 128) ? 4 : 2;
  constexpr int NI = 4;
  __shared__ __align__(16) ushort_t Ls[2][UNR * SB];

  int bx = blockIdx.x, by = blockIdx.y, bz = blockIdx.z;
  if (swiz) {
    unsigned nx = gridDim.x, ny = gridDim.y;
    unsigned id = (blockIdx.z * ny + blockIdx.y) * nx + blockIdx.x;
    unsigned pb8 = (nx * ny) >> 3;
    unsigned c = id & 7, j = id >> 3;
    bz = j / pb8;
    unsigned jb = j - bz * pb8;
    unsigned jy = jb / nx;
    by = c * (ny >> 3) + jy;
    bx = jb - jy * nx;
  }

  int m0 = by * 128, n0 = bx * BN;
  int t = threadIdx.x;
  int lane = t & 63;
  int quad = lane >> 4, l16 = lane & 15;
  int wave = t >> 6;
  int wm = (BN == 128) ? (wave >> 1) * 64 : wave * 32;
  int wn = (BN == 128) ? (wave & 1) * 64 : 0;

  f32x4 acc[MI][NI];
#pragma unroll
  for (int i = 0; i < MI; i++)
#pragma unroll
    for (int j = 0; j < NI; j++)
#pragma unroll
      for (int r = 0; r < 4; r++) acc[i][j][r] = 0.f;

  const ushort_t* gp[CPW];
  int lofs[CPW];
  int crow = lane >> 2, skoff = (lane & 3) * 8;
#pragma unroll
  for (int i = 0; i < CPW; i++) {
    int c = wave * CPW + i;
    if (c < 8) {
      gp[i] = A + (size_t)bz * sA + (size_t)(m0 + c * 16 + crow) * lda + skoff;
      lofs[i] = c * 1024 + lane * 16;
    } else {
      int slot = (c - 8) * 16 + crow;
      int arow = (slot & ~63) + ((slot & 15) * 4) + ((slot & 63) >> 4);
      gp[i] = B + (size_t)bz * sB + (size_t)(n0 + arow) * ldb + skoff;
      lofs[i] = 8192 + (c - 8) * 1024 + lane * 16;
    }
  }
  char* lbase = (char*)&Ls[0][0];

#pragma unroll
  for (int s = 0; s < UNR; s++)
#pragma unroll
    for (int i = 0; i < CPW; i++)
      gload16(gp[i] + s * 32, lbase + s * (SB * 2) + lofs[i]);

  for (int k0 = 0; k0 < K; k0 += STEP) {
    int p = (k0 / STEP) & 1;
    __syncthreads();
    if (k0 + STEP < K) {
      int pofs = (p ^ 1) * (UNR * SB * 2);
#pragma unroll
      for (int s = 0; s < UNR; s++)
#pragma unroll
        for (int i = 0; i < CPW; i++)
          gload16(gp[i] + k0 + STEP + s * 32, lbase + pofs + s * (SB * 2) + lofs[i]);
    }
#pragma unroll
    for (int s = 0; s < UNR; s++) {
      bf16x8 af[MI], bfr[NI];
#pragma unroll
      for (int i = 0; i < MI; i++)
        af[i] = *(const bf16x8*)&Ls[p][s * SB + (wm + i * 16 + l16) * 32 + quad * 8];
#pragma unroll
      for (int j = 0; j < NI; j++)
        bfr[j] = *(const bf16x8*)&Ls[p][s * SB + 4096 + (wn + j * 16 + l16) * 32 + quad * 8];
#pragma unroll
      for (int mi = 0; mi < MI; mi++)
#pragma unroll
        for (int ni = 0; ni < NI; ni++)
          acc[mi][ni] = __builtin_amdgcn_mfma_f32_16x16x32_bf16(af[mi], bfr[ni], acc[mi][ni], 0, 0, 0);
    }
  }

  size_t cbase = (size_t)bz * sC;
  int gnb = n0 + wn + l16 * 4;
  float cs4[4] = {1.f, 1.f, 1.f, 1.f};
  if (colscale) {
    float4 c4 = *(const float4*)&colscale[(size_t)bz * N + gnb];
    cs4[0] = 1.f / c4.x; cs4[1] = 1.f / c4.y; cs4[2] = 1.f / c4.z; cs4[3] = 1.f / c4.w;
  }
  float b4[4] = {0.f, 0.f, 0.f, 0.f};
  if (bias_mode == 2) {
    float4 t4 = *(const float4*)&bias[gnb];
    b4[0] = t4.x; b4[1] = t4.y; b4[2] = t4.z; b4[3] = t4.w;
  }
#pragma unroll
  for (int mi = 0; mi < MI; mi++) {
#pragma unroll
    for (int r = 0; r < 4; r++) {
      int m = m0 + wm + mi * 16 + quad * 4 + r;
      float rbias = (bias_mode == 1) ? bias[m] : 0.f;
      float v4[4];
      float rs = 0.f;
#pragma unroll
      for (int ni = 0; ni < NI; ni++) {
        float val = acc[mi][ni][r];
        if (colscale) val *= cs4[ni];
        val += (bias_mode == 2) ? b4[ni] : rbias;
        val *= scale;
        if (rowsum) { val = __expf(val) * 0.0625f; rs += val; }
        v4[ni] = val;
      }
      size_t idx = cbase + (size_t)m * ldc + gnb;
      if (omode == 1) {
        float4 rv = *(const float4*)&resid[idx];
        float4 ov = make_float4(v4[0] + rv.x, v4[1] + rv.y, v4[2] + rv.z, v4[3] + rv.w);
        *(float4*)&outF[idx] = ov;
      } else if (omode == 2) {
        unsigned w = __builtin_amdgcn_cvt_pk_fp8_f32(v4[0], v4[1], 0u, false);
        w = __builtin_amdgcn_cvt_pk_fp8_f32(v4[2], v4[3], w, true);
        *(unsigned*)&((uchar_t*)outB)[idx] = w;
      } else {
        unsigned lo = (unsigned)f2bf(v4[0]) | ((unsigned)f2bf(v4[1]) << 16);
        unsigned hi = (unsigned)f2bf(v4[2]) | ((unsigned)f2bf(v4[3]) << 16);
        *(uint2*)&outB[idx] = make_uint2(lo, hi);
      }
      if (rowsum) {
        rs += __shfl_xor(rs, 1, 64);
        rs += __shfl_xor(rs, 2, 64);
        rs += __shfl_xor(rs, 4, 64);
        rs += __shfl_xor(rs, 8, 64);
        if (l16 == 0) atomicAdd(&rowsum[(size_t)bz * 4096 + m], rs);
      }
    }
  }
}

// ---------------- fp8 C = A * B^T GEMM, 128 x BN tile, BKB in {64,128} -------
// BKB = K-bytes per LDS buffer, per launch regime (round 2/3 measurements):
//  * BKB=64 (QK, 2048 wg = 8 wg/CU): round-0 seg-transposed staging; fragment
//    b64 reads are conflict-free per 32-lane half-wave (unlike BK=32's layout,
//    which tripled SQ_LDS_BANK_CONFLICT). 32KB dbuf -> 5 wg/CU. Measured 54us.
//  * BKB=128 (PV, 512 wg = 2 wg/CU grid-limited): occupancy can't hide the
//    staging drain, so amortize it: 32 K-iters. XOR-swizzle kb^=((row&7)<<4)
//    on BOTH staging source and fragment read (rule #21). Measured ~39us
//    (vs 59us at BKB=64, 63us at BKB=32).
// B rows are column-permuted per 64-row group (staging side) so the epilogue
// writes 4 consecutive columns per lane.
// NOTE (round 1): no min-waves pin — (256,8) forced VGPR=32, acc spilled,
// 1.3GB scratch traffic, 5.4x slowdown.
// omode 0: bf16 out. omode 2: exp(scale*acc)/16 -> fp8 out + rowsum.
template <int BN, int BKB>
__global__ __launch_bounds__(256) void gemm_fp8(
    const uchar_t* __restrict__ A, long long sA, int lda,
    const uchar_t* __restrict__ B, long long sB, int ldb,
    int K, int ldc,
    void* __restrict__ outp, long long sC,
    float scale, float* __restrict__ rowsum, int swiz, int omode) {
  constexpr int SBB = (128 + BN) * BKB;    // bytes per buffer
  constexpr int BASEB = 128 * BKB;         // B-region byte offset in LDS
  constexpr int CPW = (8 + BN / 16) / 4;   // BKB=64: 1KB chunks per wave
  constexpr int NP = SBB / 4096;           // BKB=128: staging passes (exact)
  constexpr int NL = (BKB == 64) ? CPW : NP;
  constexpr int MI = (BN == 128) ? 4 : 2;
  constexpr int NI = 4;
  __shared__ __align__(16) uchar_t Ls[2][SBB];

  int bx = blockIdx.x, by = blockIdx.y, bz = blockIdx.z;
  if (swiz) {
    unsigned nx = gridDim.x, ny = gridDim.y;
    unsigned id = (blockIdx.z * ny + blockIdx.y) * nx + blockIdx.x;
    unsigned pb8 = (nx * ny) >> 3;
    unsigned c = id & 7, j = id >> 3;
    bz = j / pb8;
    unsigned jb = j - bz * pb8;
    unsigned jy = jb / nx;
    by = c * (ny >> 3) + jy;
    bx = jb - jy * nx;
  }

  int m0 = by * 128, n0 = bx * BN;
  int t = threadIdx.x;
  int lane = t & 63;
  int quad = lane >> 4, l16 = lane & 15;
  int wave = t >> 6;
  int wm = (BN == 128) ? (wave >> 1) * 64 : wave * 32;
  int wn = (BN == 128) ? (wave & 1) * 64 : 0;

  f32x4 acc[MI][NI];
#pragma unroll
  for (int i = 0; i < MI; i++)
#pragma unroll
    for (int j = 0; j < NI; j++)
#pragma unroll
      for (int r = 0; r < 4; r++) acc[i][j][r] = 0.f;

  const uchar_t* gp[NL];
  int lofs[NL];
  if constexpr (BKB == 64) {
    // seg-transposed staging: lane i stages (row i&15, 16B-seg i>>4); LDS slot
    // (r,s) = chunk*1024 + r*16 + s*256. Fragment b64 reads hit 32 banks at
    // 2 lanes/bank per half-wave = conflict-free (m136).
    int r16 = lane & 15, sseg = quad * 16;
#pragma unroll
    for (int i = 0; i < NL; i++) {
      int c = wave * CPW + i;
      if (c < 8) {
        gp[i] = A + (size_t)bz * sA + (size_t)(m0 + c * 16 + r16) * lda + sseg;
        lofs[i] = c * 1024 + lane * 16;
      } else {
        int slot = (c - 8) * 16 + r16;
        int arow = (slot & ~63) + ((slot & 15) * 4) + ((slot & 63) >> 4);
        gp[i] = B + (size_t)bz * sB + (size_t)(n0 + arow) * ldb + sseg;
        lofs[i] = BASEB + (c - 8) * 1024 + lane * 16;
      }
    }
  } else {
    // row-major 128B rows with XOR swizzle on kb (both sides, rule #21)
#pragma unroll
    for (int i = 0; i < NL; i++) {
      int o = i * 4096 + t * 16;
      int row = o >> 7;
      int kb = (o & 127) ^ ((row & 7) << 4);
      if (row < 128) {
        gp[i] = A + (size_t)bz * sA + (size_t)(m0 + row) * lda + kb;
      } else {
        int br = row - 128;
        int g = br & ~63, loc = br & 63;
        int ar = g + (loc & 15) * 4 + (loc >> 4);
        gp[i] = B + (size_t)bz * sB + (size_t)(n0 + ar) * ldb + kb;
      }
      lofs[i] = o;
    }
  }
  char* lbase = (char*)&Ls[0][0];

#pragma unroll
  for (int i = 0; i < NL; i++) gload16(gp[i], lbase + lofs[i]);

  for (int k0 = 0; k0 < K; k0 += BKB) {
    int p = (k0 / BKB) & 1;
    __syncthreads();
    if (k0 + BKB < K) {
      int pofs = (p ^ 1) * SBB;
#pragma unroll
      for (int i = 0; i < NL; i++)
        gload16(gp[i] + k0 + BKB, lbase + pofs + lofs[i]);
    }
    const uchar_t* Lp = &Ls[p][0];
    if constexpr (BKB == 64) {
      int vbase = l16 * 16 + (quad >> 1) * 256 + (quad & 1) * 8;
      long long af[2][MI], bfv[2][NI];
#pragma unroll
      for (int s = 0; s < 2; s++) {
#pragma unroll
        for (int i = 0; i < MI; i++)
          af[s][i] = *(const long long*)&Lp[wm * 64 + i * 1024 + s * 512 + vbase];
#pragma unroll
        for (int j = 0; j < NI; j++)
          bfv[s][j] = *(const long long*)&Lp[BASEB + wn * 64 + j * 1024 + s * 512 + vbase];
      }
#pragma unroll
      for (int s = 0; s < 2; s++)
#pragma unroll
        for (int mi = 0; mi < MI; mi++)
#pragma unroll
          for (int ni = 0; ni < NI; ni++)
            acc[mi][ni] = __builtin_amdgcn_mfma_f32_16x16x32_fp8_fp8(af[s][mi], bfv[s][ni], acc[mi][ni], 0, 0, 0);
    } else {
      int swz = (l16 & 7) << 4;
#pragma unroll
      for (int ks = 0; ks < 4; ks++) {
        int kx = (ks * 32 + quad * 8) ^ swz;
        long long af[MI], bfv[NI];
#pragma unroll
        for (int i = 0; i < MI; i++)
          af[i] = *(const long long*)&Lp[(wm + i * 16 + l16) * 128 + kx];
#pragma unroll
        for (int j = 0; j < NI; j++)
          bfv[j] = *(const long long*)&Lp[BASEB + (wn + j * 16 + l16) * 128 + kx];
#pragma unroll
        for (int mi = 0; mi < MI; mi++)
#pragma unroll
          for (int ni = 0; ni < NI; ni++)
            acc[mi][ni] = __builtin_amdgcn_mfma_f32_16x16x32_fp8_fp8(af[mi], bfv[ni], acc[mi][ni], 0, 0, 0);
      }
    }
  }

  size_t cbase = (size_t)bz * sC;
  int gnb = n0 + wn + l16 * 4;
#pragma unroll
  for (int mi = 0; mi < MI; mi++) {
#pragma unroll
    for (int r = 0; r < 4; r++) {
      int m = m0 + wm + mi * 16 + quad * 4 + r;
      if (omode == 2) {
        float v4[4];
        float rs = 0.f;
#pragma unroll
        for (int ni = 0; ni < NI; ni++) {
          v4[ni] = __expf(acc[mi][ni][r] * scale) * 0.0625f;
          rs += v4[ni];
        }
        unsigned w = __builtin_amdgcn_cvt_pk_fp8_f32(v4[0], v4[1], 0u, false);
        w = __builtin_amdgcn_cvt_pk_fp8_f32(v4[2], v4[3], w, true);
        *(unsigned*)&((uchar_t*)outp)[cbase + (size_t)m * ldc + gnb] = w;
        rs += __shfl_xor(rs, 1, 64);
        rs += __shfl_xor(rs, 2, 64);
        rs += __shfl_xor(rs, 4, 64);
        rs += __shfl_xor(rs, 8, 64);
        if (l16 == 0) atomicAdd(&rowsum[(size_t)bz * 4096 + m], rs);
      } else {
        unsigned lo = (unsigned)f2bf(acc[mi][0][r]) | ((unsigned)f2bf(acc[mi][1][r]) << 16);
        unsigned hi = (unsigned)f2bf(acc[mi][2][r]) | ((unsigned)f2bf(acc[mi][3][r]) << 16);
        *(uint2*)&((ushort_t*)outp)[cbase + (size_t)m * ldc + gnb] = make_uint2(lo, hi);
      }
    }
  }
}

extern "C" void kernel_launch(void* const* d_in, const int* in_sizes, int n_in,
                              void* d_out, int out_size, void* d_ws, size_t ws_size,
                              hipStream_t stream) {
  const float* x     = (const float*)d_in[0];
  const float* gamma = (const float*)d_in[1];
  const float* beta  = (const float*)d_in[2];
  const float* wq    = (const float*)d_in[3];
  const float* bq    = (const float*)d_in[4];
  const float* wk    = (const float*)d_in[5];
  const float* bk    = (const float*)d_in[6];
  const float* wv    = (const float*)d_in[7];
  const float* bv    = (const float*)d_in[8];
  const float* wo    = (const float*)d_in[9];
  const float* bo    = (const float*)d_in[10];
  float* out = (float*)d_out;

  // workspace layout
  ushort_t* wb  = (ushort_t*)d_ws;     // [wq;wk] 1024x512, wv, wo (bf16)
  ushort_t* wvb = wb + 524288;
  ushort_t* wob = wb + 786432;
  ushort_t* hnT = wb + 1048576;        // 2 x 4096 x 512 bf16
  uchar_t*  qk8 = (uchar_t*)(hnT + 4194304);  // 2 x 4096 x 1024 fp8 (q | k)
  uchar_t*  vC8 = qk8 + 8388608;       // 2 x 512 x 4096 fp8
  ushort_t* OT  = (ushort_t*)(vC8 + 4194304); // 2 x 4096 x 512 bf16
  uchar_t*  S8  = (uchar_t*)(OT + 4194304);   // 2 x 4096 x 4096 fp8 (P' = exp/16)
  float* fbuf   = (float*)(S8 + 33554432);
  float* stats  = fbuf;                // 128
  float* stats2 = fbuf + 128;          // 128
  float* qkbias = fbuf + 256;          // 1024
  float* l      = (float*)hnT;         // 2 x 4096 row sums (hnT dead after v-GEMM)

  const long long HS = 2097152;   // 4096*512 per batch
  const long long QS = 4194304;   // 4096*1024 per batch (bytes, fp8)
  const long long SS = 16777216;  // 4096*4096 per batch (bytes, fp8)
  const float scale = 0.044194173824159216f;  // 512^-0.5

  cvt_weights<<<dim3(1029), dim3(256), 0, stream>>>(wq, wk, wv, wo, bq, bk, wb, qkbias, stats2);
  gn_stats_partial<<<dim3(256), dim3(256), 0, stream>>>(x, stats2);
  gn_finalize<<<dim3(1), dim3(64), 0, stream>>>(stats2, stats);
  gn_apply<<<dim3(128, 16, 2), dim3(32, 8), 0, stream>>>(x, gamma, beta, stats, hnT);
  // qk8 = hnT * [wq;wk]^T (M=4096, N=1024, K=512), packed col bias, fp8 out
  // 512 wg = 2 wg/CU grid-limited -> UNR=2 (64-elem K-steps, 8 iters)
  gemm_abt<128, 2><<<dim3(8, 32, 2), dim3(256), 0, stream>>>(
      hnT, HS, 512, wb, 0, 512, 512, 1024, 1024, (ushort_t*)qk8, QS, qkbias, 2, 1.f,
      nullptr, nullptr, nullptr, nullptr, 1, 2);
  // vC8 = wv * hnT^T (M=512, N=4096, K=512), row bias, fp8 out; UNR=2
  gemm_abt<64, 2><<<dim3(64, 4, 2), dim3(256), 0, stream>>>(
      wvb, 0, 512, hnT, HS, 512, 512, 4096, 4096, (ushort_t*)vC8, HS, bv, 1, 1.f,
      nullptr, nullptr, nullptr, nullptr, 0, 2);
  // hnT dead; reuse as rowsum l
  zero_f32<<<dim3(32), dim3(256), 0, stream>>>(l);
  // P' = exp(scale * q*k^T)/16 fp8 + fused row sums (fp8 MFMA, M=N=4096, K=512)
  // BKB=64: 2048 wg = 8 wg/CU, seg-transposed conflict-free layout (round-0)
  gemm_fp8<128, 64><<<dim3(32, 32, 2), dim3(256), 0, stream>>>(
      qk8, QS, 1024, qk8 + 512, QS, 1024, 512, 4096, S8, SS, scale, l, 1, 2);
  // OT = P' * vC8^T (fp8 MFMA, M=4096, N=512, K=4096), bf16 out, swizzled
  // BKB=128: 512 wg = 2 wg/CU grid-limited -> amortize exposed latency
  gemm_fp8<64, 128><<<dim3(8, 32, 2), dim3(256), 0, stream>>>(
      S8, SS, 4096, vC8, HS, 4096, 4096, 512, OT, HS, 1.f, nullptr, 1, 0);
  // y = wo * (OT/l')^T + bo + x (M=512, N=4096, K=512), fp32 + residual; UNR=2
  gemm_abt<64, 2><<<dim3(64, 4, 2), dim3(256), 0, stream>>>(
      wob, 0, 512, OT, HS, 512, 512, 4096, 4096, nullptr, HS, bo, 1, 1.f,
      out, x, nullptr, l, 0, 1);
}